// Round 17
// baseline (622.666 us; speedup 1.0000x reference)
//
#include <hip/hip_runtime.h>
#include <hip/hip_bf16.h>

// ---------------------------------------------------------------------------
// GAT encoder, round 17.
//  * GEMM2/GEMM3: depth-2 pipeline with COUNTED vmcnt (T4): raw s_barrier,
//    s_waitcnt vmcnt(3) (tile t done, tile t+1 stays in flight), 2 buffers.
//    Replaces r16's __syncthreads DB whose implicit vmcnt(0) drained the
//    in-flight prefetch every iteration.
//  * carried: fused softmax+aggregate w/ depth-2 prefetch (r15/16), GEMM2
//    BM=256/8-wave (r15), single-product fp16 GEMM2/3 (r14), proj folded
//    into GEMM1 (r13), fp16 payloads + exact fused logits (r10/r12).
// ---------------------------------------------------------------------------

#define LB(x) __launch_bounds__(x)

typedef unsigned short u16;
typedef unsigned int u32;
typedef __attribute__((ext_vector_type(8))) short short8;
typedef __attribute__((ext_vector_type(8))) short bf16x8;
typedef __attribute__((ext_vector_type(8))) _Float16 f16x8;
typedef __attribute__((ext_vector_type(4))) float f32x4;

__device__ __forceinline__ float b2f(u16 u) {
    union { float f; u32 u; } x;
    x.u = ((u32)u) << 16;
    return x.f;
}
__device__ __forceinline__ u16 f2b(float f) {
    u32 u = __float_as_uint(f);
    u = (u + 0x7FFFu + ((u >> 16) & 1u)) >> 16;   // RNE
    return (u16)u;
}
__device__ __forceinline__ u16 f2h(float f) {
    union { _Float16 h; u16 u; } x;
    x.h = (_Float16)f;
    return x.u;
}
__device__ __forceinline__ float h2f(u16 u) {
    union { _Float16 h; u16 u; } x;
    x.u = u;
    return (float)x.h;
}
__device__ __forceinline__ void lds_cp16(const void* g, void* l) {
    __builtin_amdgcn_global_load_lds(
        (const __attribute__((address_space(1))) unsigned int*)g,
        (__attribute__((address_space(3))) unsigned int*)l, 16, 0, 0);
}

// ---------------- CSR build ----------------
__global__ void k_deg(const int* __restrict__ ei, int E, int Np, int* __restrict__ deg) {
    int e = blockIdx.x * blockDim.x + threadIdx.x;
    if (e >= E + Np) return;
    int dst = (e < E) ? ei[E + e] : (e - E);
    atomicAdd(&deg[dst], 1);
}

__global__ LB(256) void k_s1(const int* __restrict__ deg, int* __restrict__ row_ptr,
                             int* __restrict__ bsum, int n) {
    __shared__ int sh[256];
    int b = blockIdx.x, t = threadIdx.x;
    int i = b * 256 + t;
    int v = (i < n) ? deg[i] : 0;
    sh[t] = v;
    __syncthreads();
    #pragma unroll
    for (int off = 1; off < 256; off <<= 1) {
        int add = (t >= off) ? sh[t - off] : 0;
        __syncthreads();
        sh[t] += add;
        __syncthreads();
    }
    if (i < n) row_ptr[i + 1] = sh[t];
    if (t == 255) bsum[b] = sh[255];
}

__global__ LB(64) void k_s2(int* __restrict__ bsum, int* __restrict__ boff, int nb) {
    __shared__ int sh[64];
    int t = threadIdx.x;
    sh[t] = (t < nb) ? bsum[t] : 0;
    __syncthreads();
    #pragma unroll
    for (int off = 1; off < 64; off <<= 1) {
        int add = (t >= off) ? sh[t - off] : 0;
        __syncthreads();
        sh[t] += add;
        __syncthreads();
    }
    if (t < nb) boff[t] = (t == 0) ? 0 : sh[t - 1];
}

__global__ LB(256) void k_s3(const int* __restrict__ deg, int* __restrict__ row_ptr,
                             const int* __restrict__ boff, int* __restrict__ cursor, int n) {
    int b = blockIdx.x, t = threadIdx.x;
    int i = b * 256 + t;
    if (i == 0) row_ptr[0] = 0;
    if (i < n) {
        int inc = row_ptr[i + 1] + boff[b];
        row_ptr[i + 1] = inc;
        cursor[i] = inc - deg[i];
    }
}

__global__ void k_fill(const int* __restrict__ ei, int E, int Np,
                       int* __restrict__ cursor, int* __restrict__ col_src) {
    int e = blockIdx.x * blockDim.x + threadIdx.x;
    if (e >= E + Np) return;
    int src, dst;
    if (e < E) { src = ei[e]; dst = ei[E + e]; }
    else       { src = dst = e - E; }
    int pos = atomicAdd(&cursor[dst], 1);
    col_src[pos] = src;
}

// ---------------- fp32 -> bf16 hi/lo planes (flat) ----------------
__global__ void k_pack(const float* __restrict__ in, u16* __restrict__ hi,
                       u16* __restrict__ lo, int n4) {
    int i = blockIdx.x * blockDim.x + threadIdx.x;
    if (i >= n4) return;
    float4 v = ((const float4*)in)[i];
    ushort4 h, l;
    h.x = f2b(v.x); l.x = f2b(v.x - b2f(h.x));
    h.y = f2b(v.y); l.y = f2b(v.y - b2f(h.y));
    h.z = f2b(v.z); l.z = f2b(v.z - b2f(h.z));
    h.w = f2b(v.w); l.w = f2b(v.w - b2f(h.w));
    ((ushort4*)hi)[i] = h;
    ((ushort4*)lo)[i] = l;
}

// ---------------- weight transpose + pack ----------------
// F16S = false: bf16 hi/lo split planes. F16S = true: single fp16 plane.
template<bool F16S>
__global__ LB(256) void k_wt_pack(const float* __restrict__ W, u16* __restrict__ Whi,
                                  u16* __restrict__ Wlo, int K, int Nn) {
    __shared__ float sh[32][33];
    int n0 = blockIdx.x * 32, k0 = blockIdx.y * 32;
    int c = threadIdx.x & 31, r0 = threadIdx.x >> 5;
    #pragma unroll
    for (int r = r0; r < 32; r += 8)
        sh[r][c] = W[(size_t)(k0 + r) * Nn + n0 + c];
    __syncthreads();
    #pragma unroll
    for (int r = r0; r < 32; r += 8) {
        float v = sh[c][r];
        if (F16S) {
            Whi[(size_t)(n0 + r) * K + k0 + c] = f2h(v);
        } else {
            u16 hi = f2b(v);
            Whi[(size_t)(n0 + r) * K + k0 + c] = hi;
            Wlo[(size_t)(n0 + r) * K + k0 + c] = f2b(v - b2f(hi));
        }
    }
}

// ---------------- bias fold: bfold[n] = sum_k pb[k] * W1[k][n] ------------
__global__ LB(64) void k_bfold(const float* __restrict__ pb,
                               const u16* __restrict__ w1t_hi, const u16* __restrict__ w1t_lo,
                               float* __restrict__ bfold, int K) {
    int n = blockIdx.x;
    int lane = threadIdx.x;
    float s = 0.f;
    for (int k = lane; k < K; k += 64) {
        float w = b2f(w1t_hi[(size_t)n * K + k]) + b2f(w1t_lo[(size_t)n * K + k]);
        s = fmaf(pb[k], w, s);
    }
    #pragma unroll
    for (int off = 32; off; off >>= 1) s += __shfl_xor(s, off);
    if (lane == 0) bfold[n] = s;
}

// ---------------- MFMA GEMM: C = A[M,K] @ Bt[Nn,K]^T -----------------------
// WM waves along M (BM=WM*64), 2 along N (BN=NFR*32), threads = WM*128,
// BK=32. LDS XOR swizzle (row&7)<<4, inverse-permuted global_load_lds src.
// PREC 0: bf16 hi/lo 3-product. PREC 2: fp16 single product.
// PIPE 0: single-buffer, 2x __syncthreads per K-step.
// PIPE 2: depth-2 counted-vmcnt pipeline (raw s_barrier, vmcnt(3) leaves
//         next tile's 3 loads in flight; 2 LDS buffers). Requires LPT==3.
// OUTMODE 0: bf16 hi/lo planes. 2: fp16 plane. bias in epilogue (pre-store
// AND pre-logit). ATT: fused exact logits -> atomicAdd.
template<int WM, int NFR, int PREC, int OUTMODE, bool ATT, int PIPE>
__global__ __launch_bounds__(WM * 128)
void k_gemm_pl(const u16* __restrict__ Ahi, const u16* __restrict__ Alo,
               const u16* __restrict__ Bhi, const u16* __restrict__ Blo,
               const float* __restrict__ bias,
               u16* __restrict__ Chi, u16* __restrict__ Clo,
               u16* __restrict__ Cf16,
               const float* __restrict__ att_s, const float* __restrict__ att_d,
               float* __restrict__ a_src, float* __restrict__ a_dst,
               int HH, int M, int K, int Nn) {
    constexpr int BM = WM * 64;
    constexpr int BN = NFR * 32;
    constexpr int T  = WM * 128;
    constexpr int BITER = ((NFR * 128) / T > 0) ? (NFR * 128) / T : 1;
    constexpr int NBUF = (PIPE == 2) ? 2 : 1;
    constexpr int ASZ = BM * 32;          // u16 elems per A plane buffer
    constexpr int BSZ = BN * 32;
    static_assert(PIPE != 2 || (PREC == 2 && 2 + BITER == 3), "PIPE2 needs LPT==3");
    __shared__ u16 AsHi[NBUF * ASZ];
    __shared__ u16 AsLo[(PREC == 0) ? ASZ : 8];
    __shared__ u16 BsHi[NBUF * BSZ];
    __shared__ u16 BsLo[(PREC == 0) ? BSZ : 8];
    const int tid  = threadIdx.x;
    const int lane = tid & 63;
    const int w    = tid >> 6;
    const int wr   = w >> 1;          // 0..WM-1
    const int wc   = w & 1;
    const int row0 = blockIdx.y * BM;
    const int col0 = blockIdx.x * BN;
    const int ln15 = lane & 15;
    const int lq   = lane >> 4;

    f32x4 acc[4][NFR];
    #pragma unroll
    for (int m = 0; m < 4; ++m)
        #pragma unroll
        for (int n = 0; n < NFR; ++n) acc[m][n] = (f32x4){0.f, 0.f, 0.f, 0.f};

    auto STAGE = [&](int k0, int buf) {
        size_t ab = (size_t)buf * ASZ * 2;     // byte offsets
        size_t bb = (size_t)buf * BSZ * 2;
        #pragma unroll
        for (int i = 0; i < 2; ++i) {
            int c = i * T + tid;
            int r  = 2 * (c >> 3) + (((c >> 2) ^ (c >> 4)) & 1);   // inverse swizzle
            int kc = (c & 3) ^ (r & 3);
            int gra = row0 + r; if (gra >= M) gra = M - 1;          // tail clamp
            size_t ga = (size_t)gra * K + k0 + kc * 8;
            lds_cp16(Ahi + ga, (char*)AsHi + ab + c * 16);
            if (PREC == 0) lds_cp16(Alo + ga, (char*)AsLo + c * 16);
        }
        #pragma unroll
        for (int i = 0; i < BITER; ++i) {
            int c = i * T + tid;
            int r  = 2 * (c >> 3) + (((c >> 2) ^ (c >> 4)) & 1);
            int kc = (c & 3) ^ (r & 3);
            size_t gb = (size_t)(col0 + r) * K + k0 + kc * 8;
            lds_cp16(Bhi + gb, (char*)BsHi + bb + c * 16);
            if (PREC == 0) lds_cp16(Blo + gb, (char*)BsLo + c * 16);
        }
    };

    auto COMPUTE = [&](int buf) {
        size_t ab = (size_t)buf * ASZ * 2;
        size_t bb = (size_t)buf * BSZ * 2;
        if (PREC == 0) {
            bf16x8 ah[4], al[4], bh[NFR], bl[NFR];
            #pragma unroll
            for (int m = 0; m < 4; ++m) {
                int row = wr * 64 + m * 16 + ln15;
                size_t byo = (size_t)((row * 64 + lq * 16) ^ ((row & 7) << 4));
                ah[m] = *(const bf16x8*)((const char*)AsHi + ab + byo);
                al[m] = *(const bf16x8*)((const char*)AsLo + byo);
            }
            #pragma unroll
            for (int n = 0; n < NFR; ++n) {
                int row = wc * (NFR * 16) + n * 16 + ln15;
                size_t byo = (size_t)((row * 64 + lq * 16) ^ ((row & 7) << 4));
                bh[n] = *(const bf16x8*)((const char*)BsHi + bb + byo);
                bl[n] = *(const bf16x8*)((const char*)BsLo + byo);
            }
            #pragma unroll
            for (int m = 0; m < 4; ++m)
                #pragma unroll
                for (int n = 0; n < NFR; ++n) {
                    acc[m][n] = __builtin_amdgcn_mfma_f32_16x16x32_bf16(al[m], bh[n], acc[m][n], 0, 0, 0);
                    acc[m][n] = __builtin_amdgcn_mfma_f32_16x16x32_bf16(ah[m], bl[n], acc[m][n], 0, 0, 0);
                    acc[m][n] = __builtin_amdgcn_mfma_f32_16x16x32_bf16(ah[m], bh[n], acc[m][n], 0, 0, 0);
                }
        } else {
            f16x8 a[4], b[NFR];
            #pragma unroll
            for (int m = 0; m < 4; ++m) {
                int row = wr * 64 + m * 16 + ln15;
                size_t byo = (size_t)((row * 64 + lq * 16) ^ ((row & 7) << 4));
                a[m] = *(const f16x8*)((const char*)AsHi + ab + byo);
            }
            #pragma unroll
            for (int n = 0; n < NFR; ++n) {
                int row = wc * (NFR * 16) + n * 16 + ln15;
                size_t byo = (size_t)((row * 64 + lq * 16) ^ ((row & 7) << 4));
                b[n] = *(const f16x8*)((const char*)BsHi + bb + byo);
            }
            #pragma unroll
            for (int m = 0; m < 4; ++m)
                #pragma unroll
                for (int n = 0; n < NFR; ++n)
                    acc[m][n] = __builtin_amdgcn_mfma_f32_16x16x32_f16(a[m], b[n], acc[m][n], 0, 0, 0);
        }
    };

    if (PIPE == 2) {
        const int nt = K >> 5;
        STAGE(0, 0);
        if (nt > 1) STAGE(32, 1);
        for (int t = 0; t < nt; ++t) {
            if (t + 1 < nt) {
                asm volatile("s_waitcnt vmcnt(3)" ::: "memory");  // tile t done; t+1 in flight
            } else {
                asm volatile("s_waitcnt vmcnt(0)" ::: "memory");
            }
            __builtin_amdgcn_s_barrier();          // all threads have tile t resident
            __builtin_amdgcn_sched_barrier(0);
            COMPUTE(t & 1);
            __builtin_amdgcn_sched_barrier(0);
            __builtin_amdgcn_s_barrier();          // all done reading buf[t&1]
            if (t + 2 < nt) STAGE((t + 2) << 5, t & 1);
        }
    } else {
        for (int k0 = 0; k0 < K; k0 += 32) {
            STAGE(k0, 0);
            __syncthreads();
            COMPUTE(0);
            __syncthreads();
        }
    }

    // D: col = lane&15, row = (lane>>4)*4 + j  [m89/m91-verified]
    #pragma unroll
    for (int m = 0; m < 4; ++m) {
        #pragma unroll
        for (int n = 0; n < NFR; ++n) {
            int gc = col0 + wc * (NFR * 16) + n * 16 + ln15;
            float badd = bias ? bias[gc] : 0.f;
            #pragma unroll
            for (int j = 0; j < 4; ++j) {
                int gr = row0 + wr * 64 + m * 16 + lq * 4 + j;
                if (gr < M) {
                    float v = acc[m][n][j] + badd;
                    size_t o = (size_t)gr * Nn + gc;
                    if (OUTMODE == 0) {
                        u16 hi = f2b(v);
                        Chi[o] = hi;
                        Clo[o] = f2b(v - b2f(hi));
                    } else {
                        Cf16[o] = f2h(v);
                    }
                }
            }
        }
    }

    if (ATT) {
        float atts[NFR], attd[NFR], bb[NFR];
        #pragma unroll
        for (int n = 0; n < NFR; ++n) {
            int gc = col0 + wc * (NFR * 16) + n * 16 + ln15;
            atts[n] = att_s[gc];
            attd[n] = att_d[gc];
            bb[n]   = bias ? bias[gc] : 0.f;
        }
        const int head = (col0 + wc * (NFR * 16)) >> 9;   // /512, wave-uniform
        #pragma unroll
        for (int m = 0; m < 4; ++m) {
            #pragma unroll
            for (int j = 0; j < 4; ++j) {
                int gr = row0 + wr * 64 + m * 16 + lq * 4 + j;
                float s1 = 0.f, s2 = 0.f;
                #pragma unroll
                for (int n = 0; n < NFR; ++n) {
                    float v = acc[m][n][j] + bb[n];
                    s1 = fmaf(v, atts[n], s1);
                    s2 = fmaf(v, attd[n], s2);
                }
                #pragma unroll
                for (int off = 1; off < 16; off <<= 1) {
                    s1 += __shfl_xor(s1, off);
                    s2 += __shfl_xor(s2, off);
                }
                if (ln15 == 0 && gr < M) {
                    atomicAdd(&a_src[gr * HH + head], s1);
                    atomicAdd(&a_dst[gr * HH + head], s2);
                }
            }
        }
    }
}

// ---------------- fused softmax + aggregate (one block per dst) ------------
// HH waves; wave w == head w (64 lanes x 8 feats = 512 = C). Alpha computed
// in-register, parked in LDS; gather loop with depth-2 paired prefetch.
template <int HH, int OMODE, bool ELU_>
__global__ __launch_bounds__(HH * 64)
void k_sagg(const int* __restrict__ row_ptr, const int* __restrict__ col_src,
            const float* __restrict__ a_src, const float* __restrict__ a_dst,
            const u16* __restrict__ hf, const float* __restrict__ bias,
            u16* __restrict__ Oh, float* __restrict__ Of, int C) {
    __shared__ float sal[HH * 64];
    const int d    = blockIdx.x;
    const int tid  = threadIdx.x;
    const int w    = tid >> 6;       // head
    const int lane = tid & 63;
    const int F    = HH * C;
    const int o    = tid * 8;
    const int s = row_ptr[d], eend = row_ptr[d + 1];
    const int cnt = eend - s;
    const float adh = a_dst[d * HH + w];

    float acc[8];
    #pragma unroll
    for (int j = 0; j < 8; ++j) acc[j] = 0.f;

    if (cnt <= 64) {
        bool act = lane < cnt;
        float av = act ? a_src[col_src[s + lane] * HH + w] : 0.f;
        float x = av + adh;
        x = (x > 0.f) ? x : 0.2f * x;
        float v = act ? x : -1e30f;
        float m = v;
        #pragma unroll
        for (int off = 32; off; off >>= 1) m = fmaxf(m, __shfl_xor(m, off));
        float e_ = act ? __expf(v - m) : 0.f;
        float sum = e_;
        #pragma unroll
        for (int off = 32; off; off >>= 1) sum += __shfl_xor(sum, off);
        if (act) sal[w * 64 + lane] = e_ / sum;
        __syncthreads();

        // depth-2 paired-prefetch gather (consume strictly in edge order)
        short8 v0, v1; float a0, a1;
        if (cnt > 0) { v0 = *(const short8*)(hf + (size_t)col_src[s] * F + o); a0 = sal[w * 64]; }
        if (cnt > 1) { v1 = *(const short8*)(hf + (size_t)col_src[s + 1] * F + o); a1 = sal[w * 64 + 1]; }
        int i = 0;
        for (; i + 2 <= cnt; i += 2) {
            short8 t0, t1; float b0, b1;
            bool m0 = (i + 2 < cnt), m1 = (i + 3 < cnt);   // block-uniform
            if (m0) { t0 = *(const short8*)(hf + (size_t)col_src[s + i + 2] * F + o); b0 = sal[w * 64 + i + 2]; }
            if (m1) { t1 = *(const short8*)(hf + (size_t)col_src[s + i + 3] * F + o); b1 = sal[w * 64 + i + 3]; }
            #pragma unroll
            for (int j = 0; j < 8; ++j) acc[j] = fmaf(a0, h2f((u16)v0[j]), acc[j]);
            #pragma unroll
            for (int j = 0; j < 8; ++j) acc[j] = fmaf(a1, h2f((u16)v1[j]), acc[j]);
            if (m0) { v0 = t0; a0 = b0; }
            if (m1) { v1 = t1; a1 = b1; }
        }
        if (i < cnt) {   // odd tail: edge i lives in slot 0
            #pragma unroll
            for (int j = 0; j < 8; ++j) acc[j] = fmaf(a0, h2f((u16)v0[j]), acc[j]);
        }
    } else {
        // generic fallback (deg > 64): 3-pass + chunked aggregate
        float m = -1e30f;
        for (int e = s + lane; e < eend; e += 64) {
            float x = a_src[col_src[e] * HH + w] + adh;
            x = (x > 0.f) ? x : 0.2f * x;
            m = fmaxf(m, x);
        }
        #pragma unroll
        for (int off = 32; off; off >>= 1) m = fmaxf(m, __shfl_xor(m, off));
        float sum = 0.f;
        for (int e = s + lane; e < eend; e += 64) {
            float x = a_src[col_src[e] * HH + w] + adh;
            x = (x > 0.f) ? x : 0.2f * x;
            sum += __expf(x - m);
        }
        #pragma unroll
        for (int off = 32; off; off >>= 1) sum += __shfl_xor(sum, off);
        float inv = 1.0f / sum;
        for (int base = s; base < eend; base += 64) {
            int e = base + lane;
            if (e < eend) {
                float x = a_src[col_src[e] * HH + w] + adh;
                x = (x > 0.f) ? x : 0.2f * x;
                sal[w * 64 + lane] = __expf(x - m) * inv;
            }
            __syncthreads();
            int nn = (eend - base < 64) ? (eend - base) : 64;
            for (int i = 0; i < nn; ++i) {
                int src = col_src[base + i];
                float a = sal[w * 64 + i];
                short8 vv = *(const short8*)(hf + (size_t)src * F + o);
                #pragma unroll
                for (int j = 0; j < 8; ++j)
                    acc[j] = fmaf(a, h2f((u16)vv[j]), acc[j]);
            }
            __syncthreads();
        }
    }

    #pragma unroll
    for (int j = 0; j < 8; ++j) {
        acc[j] += bias[o + j];
        if (ELU_) acc[j] = (acc[j] > 0.f) ? acc[j] : __expf(acc[j]) - 1.f;
    }
    if (OMODE == 0) {
        short8 r;
        #pragma unroll
        for (int j = 0; j < 8; ++j) r[j] = (short)f2h(acc[j]);
        *(short8*)(Oh + (size_t)d * F + o) = r;
    } else {
        float* po = Of + (size_t)d * F + o;
        #pragma unroll
        for (int j4 = 0; j4 < 2; ++j4) {
            float4 r;
            r.x = acc[j4 * 4 + 0]; r.y = acc[j4 * 4 + 1];
            r.z = acc[j4 * 4 + 2]; r.w = acc[j4 * 4 + 3];
            *(float4*)&po[j4 * 4] = r;
        }
    }
}

// ---------------------------------------------------------------------------
extern "C" void kernel_launch(void* const* d_in, const int* in_sizes, int n_in,
                              void* d_out, int out_size, void* d_ws, size_t ws_size,
                              hipStream_t stream) {
    const float* x      = (const float*)d_in[0];
    const int*   ei     = (const int*)d_in[1];
    const float* proj_W = (const float*)d_in[2];
    const float* proj_b = (const float*)d_in[3];
    const float* W1  = (const float*)d_in[4];
    const float* as1 = (const float*)d_in[5];
    const float* ad1 = (const float*)d_in[6];
    const float* b1  = (const float*)d_in[7];
    const float* W2  = (const float*)d_in[8];
    const float* as2 = (const float*)d_in[9];
    const float* ad2 = (const float*)d_in[10];
    const float* b2  = (const float*)d_in[11];
    const float* W3  = (const float*)d_in[12];
    const float* as3 = (const float*)d_in[13];
    const float* ad3 = (const float*)d_in[14];
    const float* b3  = (const float*)d_in[15];

    const int N  = in_sizes[0] / 256;   // 10000
    const int E  = in_sizes[1] / 2;     // 160000
    const int Ep = E + N;
    const int NB = (N + 255) / 256;     // 40 scan blocks

    size_t off = 0;
    auto alloc = [&](size_t bytes) -> void* {
        void* p = (char*)d_ws + off;
        off += (bytes + 255) & ~(size_t)255;
        return p;
    };
    u16* bufX    = (u16*)alloc((size_t)N * 2048 * 2);   // fp16 h  (40 MB)
    u16* bufY    = (u16*)alloc((size_t)N * 2048 * 2);   // fp16 h' (40 MB)
    u16* xb_hi   = (u16*)alloc((size_t)N * 256 * 2);
    u16* xb_lo   = (u16*)alloc((size_t)N * 256 * 2);
    u16* pw_hi   = (u16*)alloc((size_t)256 * 512 * 2);  // proj_W flat planes
    u16* pw_lo   = (u16*)alloc((size_t)256 * 512 * 2);
    u16* wf_hi   = (u16*)alloc((size_t)2048 * 256 * 2); // Wfold^T planes
    u16* wf_lo   = (u16*)alloc((size_t)2048 * 256 * 2);
    float* bfold   = (float*)alloc((size_t)2048 * 4);
    float* att_z   = (float*)alloc((size_t)N * 18 * 4); // a_src/a_dst x3 layers
    int*   deg     = (int*)alloc((size_t)N * 4);
    int*   cursor  = (int*)alloc((size_t)N * 4);
    int*   row_ptr = (int*)alloc((size_t)(N + 1) * 4);
    int*   col_src = (int*)alloc((size_t)Ep * 4);
    int*   bsum    = (int*)alloc((size_t)NB * 4);
    int*   boff    = (int*)alloc((size_t)NB * 4);
    (void)ws_size;

    float* a_src1 = att_z;
    float* a_dst1 = att_z + (size_t)N * 4;
    float* a_src2 = att_z + (size_t)N * 8;
    float* a_dst2 = att_z + (size_t)N * 12;
    float* a_src3 = att_z + (size_t)N * 16;
    float* a_dst3 = att_z + (size_t)N * 17;

    // JIT weight planes in d_out (16.78 MB <= 20.48 MB); fully overwritten
    // by the final aggregate afterwards.
    u16* whi = (u16*)d_out;
    u16* wlo = (u16*)d_out + (size_t)2048 * 2048;

    // ---- CSR build + zero att accumulators ----
    hipMemsetAsync(deg, 0, (size_t)N * 4, stream);
    hipMemsetAsync(att_z, 0, (size_t)N * 18 * 4, stream);
    int eb = (Ep + 255) / 256;
    k_deg<<<eb, 256, 0, stream>>>(ei, E, N, deg);
    k_s1<<<NB, 256, 0, stream>>>(deg, row_ptr, bsum, N);
    k_s2<<<1, 64, 0, stream>>>(bsum, boff, NB);
    k_s3<<<NB, 256, 0, stream>>>(deg, row_ptr, boff, cursor, N);
    k_fill<<<eb, 256, 0, stream>>>(ei, E, N, cursor, col_src);

    const int MB1 = (N + 127) / 128;  // 79
    const int MB2 = (N + 255) / 256;  // 40

    // ---- pack x [N,256] and proj_W (flat [256x512]) into bf16 planes ----
    k_pack<<<(N * 256 / 4 + 255) / 256, 256, 0, stream>>>(x, xb_hi, xb_lo, N * 256 / 4);
    k_pack<<<(256 * 512 / 4 + 255) / 256, 256, 0, stream>>>(proj_W, pw_hi, pw_lo, 256 * 512 / 4);

    // ---- W1^T planes; fold: Wfold^T = W1^T @ proj_W^T; bfold = pb @ W1 ----
    k_wt_pack<false><<<dim3(2048 / 32, 512 / 32), 256, 0, stream>>>(W1, whi, wlo, 512, 2048);
    k_bfold<<<2048, 64, 0, stream>>>(proj_b, whi, wlo, bfold, 512);
    k_gemm_pl<2, 2, 0, 0, false, 0><<<dim3(256 / 64, 2048 / 128), 256, 0, stream>>>(
        whi, wlo, pw_hi, pw_lo, nullptr, wf_hi, wf_lo, nullptr,
        nullptr, nullptr, nullptr, nullptr, 0, 2048, 512, 256);

    // ---- layer 1 (K=256 folded; split-bf16 3-product; fp16 h out;
    //      exact fused logits include bfold) ----
    k_gemm_pl<2, 4, 0, 2, true, 0><<<dim3(2048 / 128, MB1), 256, 0, stream>>>(
        xb_hi, xb_lo, wf_hi, wf_lo, bfold, nullptr, nullptr, bufX,
        as1, ad1, a_src1, a_dst1, 4, N, 256, 2048);
    k_sagg<4, 0, true><<<N, 256, 0, stream>>>(row_ptr, col_src, a_src1, a_dst1,
                                              bufX, b1, bufY, nullptr, 512);

    // ---- layer 2 (fp16 single-product; BM=256, 8 waves; counted-vmcnt) ----
    k_wt_pack<true><<<dim3(2048 / 32, 2048 / 32), 256, 0, stream>>>(W2, whi, nullptr, 2048, 2048);
    k_gemm_pl<4, 4, 2, 2, true, 2><<<dim3(2048 / 128, MB2), 512, 0, stream>>>(
        bufY, nullptr, whi, nullptr, nullptr, nullptr, nullptr, bufX,
        as2, ad2, a_src2, a_dst2, 4, N, 2048, 2048);
    k_sagg<4, 0, true><<<N, 256, 0, stream>>>(row_ptr, col_src, a_src2, a_dst2,
                                              bufX, b2, bufY, nullptr, 512);

    // ---- layer 3 (fp16 single-product; counted-vmcnt; 1 head) ----
    k_wt_pack<true><<<dim3(512 / 32, 2048 / 32), 256, 0, stream>>>(W3, whi, nullptr, 2048, 512);
    k_gemm_pl<2, 2, 2, 2, true, 2><<<dim3(512 / 64, MB1), 256, 0, stream>>>(
        bufY, nullptr, whi, nullptr, nullptr, nullptr, nullptr, bufX,
        as3, ad3, a_src3, a_dst3, 1, N, 2048, 512);
    k_sagg<1, 1, false><<<N, 64, 0, stream>>>(row_ptr, col_src, a_src3, a_dst3,
                                              bufX, b3, nullptr, (float*)d_out, 512);
}